// Round 3
// baseline (109.037 us; speedup 1.0000x reference)
//
#include <hip/hip_runtime.h>
#include <math.h>

#define RATE 0.1f
#define INV_KEEP (1.0f / 0.9f)
#define EPS 1e-4f
#define CLIP_MAG 8.0f
#define ACOSH_MIN 1.0001f

// Native vector type — accepted by __builtin_nontemporal_{load,store}
typedef float floatx4 __attribute__((ext_vector_type(4)));

// Branch-free fast transcendentals on hardware v_exp_f32 / v_log_f32 / v_rcp_f32.
__device__ __forceinline__ float fast_exp(float x) {
    return __builtin_amdgcn_exp2f(x * 1.44269504088896341f);
}
__device__ __forceinline__ float fast_log(float x) {
    return __builtin_amdgcn_logf(x) * 0.69314718055994531f;
}
__device__ __forceinline__ float fast_rcp(float x) {
    return __builtin_amdgcn_rcpf(x);
}

// One wave (64 lanes) per row of 512 floats: 2 float4 loads per lane per input.
// Everything stays in registers; single global pass; branch-free scalar tail.
__global__ __launch_bounds__(256) void hyp_dropout_kernel(
    const float* __restrict__ vecs,
    const float* __restrict__ curv,
    const float* __restrict__ mask,
    float* __restrict__ out,
    int nrows)
{
    const int wave = blockIdx.x * 4 + (threadIdx.x >> 6);
    const int lane = threadIdx.x & 63;
    if (wave >= nrows) return;

    const size_t base = (size_t)wave * 512;
    const floatx4* vr = (const floatx4*)(vecs + base);
    const floatx4* mr = (const floatx4*)(mask + base);

    const floatx4 va = __builtin_nontemporal_load(&vr[lane]);
    const floatx4 vb = __builtin_nontemporal_load(&vr[lane + 64]);
    const floatx4 ma = __builtin_nontemporal_load(&mr[lane]);
    const floatx4 mb = __builtin_nontemporal_load(&mr[lane + 64]);

    // coordinate 0 (lane 0, va.x) is excluded by _proj: zero it before everything
    const float a0 = (lane == 0) ? 0.f : va.x;

    // masked values (cndmask, no flag multiplies)
    const float xa0 = (ma.x >= RATE) ? a0   : 0.f;
    const float xa1 = (ma.y >= RATE) ? va.y : 0.f;
    const float xa2 = (ma.z >= RATE) ? va.z : 0.f;
    const float xa3 = (ma.w >= RATE) ? va.w : 0.f;
    const float xb0 = (mb.x >= RATE) ? vb.x : 0.f;
    const float xb1 = (mb.y >= RATE) ? vb.y : 0.f;
    const float xb2 = (mb.z >= RATE) ? vb.z : 0.f;
    const float xb3 = (mb.w >= RATE) ? vb.w : 0.f;

    // s2 = sum x_j^2 (j>=1), m2 = sum keep_j * x_j^2 (j>=1) — two ILP chains
    float s2 = a0 * a0;
    float m2 = xa0 * xa0;
    s2 = fmaf(va.y, va.y, s2); m2 = fmaf(xa1, xa1, m2);
    s2 = fmaf(va.z, va.z, s2); m2 = fmaf(xa2, xa2, m2);
    s2 = fmaf(va.w, va.w, s2); m2 = fmaf(xa3, xa3, m2);
    s2 = fmaf(vb.x, vb.x, s2); m2 = fmaf(xb0, xb0, m2);
    s2 = fmaf(vb.y, vb.y, s2); m2 = fmaf(xb1, xb1, m2);
    s2 = fmaf(vb.z, vb.z, s2); m2 = fmaf(xb2, xb2, m2);
    s2 = fmaf(vb.w, vb.w, s2); m2 = fmaf(xb3, xb3, m2);

    // 64-lane butterfly reduction of both sums (independent -> ILP)
    #pragma unroll
    for (int off = 32; off > 0; off >>= 1) {
        s2 += __shfl_xor(s2, off, 64);
        m2 += __shfl_xor(m2, off, 64);
    }

    const float c = curv[0];
    const float sqrt_c = sqrtf(c);
    const float rc = fast_rcp(sqrt_c);

    // logmap scalars: dist = sqrt_c * acosh(max(v0/sqrt_c - eps, 1.0001))
    const float v0 = sqrtf(c + s2);
    const float arg = fmaxf(fmaf(v0, rc, -EPS), ACOSH_MIN);
    const float acosh_arg = fast_log(arg + sqrtf(fmaf(arg, arg, -1.f)));
    const float dist = sqrt_c * acosh_arg;
    const float k = dist * fast_rcp(sqrtf(s2) + EPS) * INV_KEEP;  // logmap scale * dropout scale

    // expmap scalars; k >= 0 so ||dropped|| = k * sqrt(m2)
    const float snv = fmaf(k * sqrtf(m2), rc, EPS);
    const float snv_c = fminf(fmaxf(snv, -CLIP_MAG), CLIP_MAG);
    const float e  = fast_exp(snv_c);
    const float ei = fast_rcp(e);
    const float sh = 0.5f * (e - ei) * fast_rcp(snv);   // sinh(snv_c)/snv
    const float ch = 0.5f * (e + ei) * sqrt_c;          // cosh(snv_c)*sqrt_c -> out[0]

    // out[j] = sh * k * keep_j * x_j  (j>=1);  out[0] = ch
    const float w = sh * k;
    floatx4 oa, ob;
    oa.x = (lane == 0) ? ch : w * xa0;
    oa.y = w * xa1;
    oa.z = w * xa2;
    oa.w = w * xa3;
    ob.x = w * xb0;
    ob.y = w * xb1;
    ob.z = w * xb2;
    ob.w = w * xb3;

    floatx4* orow = (floatx4*)(out + base);
    __builtin_nontemporal_store(oa, &orow[lane]);
    __builtin_nontemporal_store(ob, &orow[lane + 64]);
}

extern "C" void kernel_launch(void* const* d_in, const int* in_sizes, int n_in,
                              void* d_out, int out_size, void* d_ws, size_t ws_size,
                              hipStream_t stream) {
    const float* vecs = (const float*)d_in[0];
    const float* curv = (const float*)d_in[1];
    const float* mask = (const float*)d_in[2];
    float* out = (float*)d_out;

    const int nrows = in_sizes[0] / 512;          // 16384
    const int waves_per_block = 4;                // 256 threads
    const int grid = (nrows + waves_per_block - 1) / waves_per_block;

    hyp_dropout_kernel<<<grid, 256, 0, stream>>>(vecs, curv, mask, out, nrows);
}